// Round 1
// baseline (279.813 us; speedup 1.0000x reference)
//
#include <hip/hip_runtime.h>
#include <math.h>

#define BB 16
#define QQ 300
#define CC 256
#define NHH 8
#define DHH 32
#define SUMPP 16
#define SSS 8500
#define GQ 10
#define QT (QQ / GQ) // 30

// ---------------------------------------------------------------------------
// Kernel A: offsets GEMM + attn GEMM + softmax + loc computation.
// 384 threads: t<256 -> one offset output (h,p,xy) each; t>=256 -> one attn
// logit (h,p) each. 10 queries per block; hidden-state reads are
// block-uniform -> s_load. Softmax via 16-lane shuffle butterfly (no LDS).
// ---------------------------------------------------------------------------
__global__ __launch_bounds__(384) void precompute_kernel(
    const float* __restrict__ hs,      // (B,Q,C)
    const float* __restrict__ refp,    // (B,Q,1,4)
    const float* __restrict__ off_k,   // (C,NH,SUMP,2) = (C,256)
    const float* __restrict__ off_b,   // (NH,SUMP,2) = 256
    const float* __restrict__ attn_k,  // (C,NH,SUMP) = (C,128)
    const float* __restrict__ attn_b,  // (NH,SUMP) = 128
    const float* __restrict__ nps,     // (SUMP)
    float* __restrict__ loc_out,       // (B,Q,NH,SUMP,2)
    float* __restrict__ attn_out)      // (B,Q,NH,SUMP)
{
    const int t = threadIdx.x;
    const int blk = blockIdx.x;            // 0..B*QT-1
    const int b = blk / QT;
    const int q0 = (blk % QT) * GQ;
    const float* hsb = hs + ((size_t)b * QQ + q0) * CC;

    float acc[GQ];
#pragma unroll
    for (int g = 0; g < GQ; ++g) acc[g] = 0.f;

    if (t < 256) {
        const float* kcol = off_k + t;
#pragma unroll 4
        for (int c = 0; c < CC; ++c) {
            const float k = kcol[c * 256];
#pragma unroll
            for (int g = 0; g < GQ; ++g)
                acc[g] = fmaf(hsb[g * CC + c], k, acc[g]);
        }
        const int p = (t >> 1) & 15;
        const float scale = nps[p] * 0.5f;  // OFFSET_SCALE = 0.5
        const float bias = off_b[t];
        const bool isy = (t & 1);
#pragma unroll
        for (int g = 0; g < GQ; ++g) {
            const float4 r = *(const float4*)(refp + ((size_t)b * QQ + q0 + g) * 4);
            const float center = isy ? r.y : r.x;
            const float wh     = isy ? r.w : r.z;
            loc_out[((size_t)b * QQ + q0 + g) * 256 + t] =
                fmaf((acc[g] + bias) * scale, wh, center);
        }
    } else {
        const int j = t - 256;             // 0..127 = h*16+p
        const float* kcol = attn_k + j;
#pragma unroll 4
        for (int c = 0; c < CC; ++c) {
            const float k = kcol[c * 128];
#pragma unroll
            for (int g = 0; g < GQ; ++g)
                acc[g] = fmaf(hsb[g * CC + c], k, acc[g]);
        }
        const float bias = attn_b[j];
#pragma unroll
        for (int g = 0; g < GQ; ++g) {
            const float logit = acc[g] + bias;
            float m = logit;
#pragma unroll
            for (int o = 1; o < 16; o <<= 1)
                m = fmaxf(m, __shfl_xor(m, o));
            const float e = __expf(logit - m);
            float s = e;
#pragma unroll
            for (int o = 1; o < 16; o <<= 1)
                s += __shfl_xor(s, o);
            attn_out[((size_t)b * QQ + q0 + g) * 128 + j] = e / s;
        }
    }
}

// ---------------------------------------------------------------------------
// Kernel B: bilinear sampling + attention-weighted accumulation.
// 256 threads = 4 queries x (8 heads x 8 threads); each thread owns float4 of
// DH. loc/attn staged in LDS transposed to [q][p][h] so per-point broadcast
// reads hit 8 consecutive banks (conflict-free).
// ---------------------------------------------------------------------------
__global__ __launch_bounds__(256) void sample_kernel(
    const float* __restrict__ enc,   // (B,S,NH,DH) = (B,S,256)
    const float* __restrict__ loc,   // (B,Q,NH,SUMP,2)
    const float* __restrict__ attn,  // (B,Q,NH,SUMP)
    float* __restrict__ out)         // (B,Q,256)
{
    __shared__ float sh_lx[4 * SUMPP * NHH];  // [qs][p][h]
    __shared__ float sh_ly[4 * SUMPP * NHH];
    __shared__ float sh_a[4 * SUMPP * NHH];

    const int t = threadIdx.x;
    const int blk = blockIdx.x;              // B*Q/4 = 1200
    const int b = blk / (QQ / 4);
    const int q0 = (blk % (QQ / 4)) * 4;
    const size_t qbase = (size_t)b * QQ + q0;

    // Stage loc (1024 floats) and attn (512 floats), transposing to [q][p][h].
#pragma unroll
    for (int k = 0; k < 4; ++k) {
        const int i = t + k * 256;
        const float v = loc[qbase * 256 + i];
        const int q_i = i >> 8;
        const int r = i & 255;
        const int h_i = r >> 5;
        const int rem = r & 31;
        const int p_i = rem >> 1;
        if (rem & 1) sh_ly[q_i * 128 + p_i * 8 + h_i] = v;
        else         sh_lx[q_i * 128 + p_i * 8 + h_i] = v;
    }
#pragma unroll
    for (int k = 0; k < 2; ++k) {
        const int i = t + k * 256;
        const float v = attn[qbase * 128 + i];
        const int q_i = i >> 7;
        const int r = i & 127;
        const int h_i = r >> 4;
        const int p_i = r & 15;
        sh_a[q_i * 128 + p_i * 8 + h_i] = v;
    }
    __syncthreads();

    const int qs = t >> 6;                   // wave id = query sub-index
    const int lane = t & 63;
    const int h = lane >> 3;
    const int d4 = (lane & 7) << 2;
    const float* vb = enc + (size_t)b * SSS * 256 + h * 32 + d4;

    float4 acc = {0.f, 0.f, 0.f, 0.f};

    const int   HWs[4]    = {80, 40, 20, 10};
    const int   starts[4] = {0, 6400, 8000, 8400};

    int p = 0;
#pragma unroll
    for (int lvl = 0; lvl < 4; ++lvl) {
        const int Wd = HWs[lvl];
        const float Wf = (float)Wd;
        const int st = starts[lvl];
#pragma unroll
        for (int pp = 0; pp < 4; ++pp, ++p) {
            const float locx = sh_lx[qs * 128 + p * 8 + h];
            const float locy = sh_ly[qs * 128 + p * 8 + h];
            const float aw   = sh_a [qs * 128 + p * 8 + h];

            const float x = locx * Wf - 0.5f;
            const float y = locy * Wf - 0.5f;
            const float x0f = floorf(x), y0f = floorf(y);
            const float lx = x - x0f, ly = y - y0f;
            const int x0 = (int)x0f, y0 = (int)y0f;
            const int x1 = x0 + 1, y1 = y0 + 1;
            const float w00 = (1.f - lx) * (1.f - ly);
            const float w10 = lx * (1.f - ly);
            const float w01 = (1.f - lx) * ly;
            const float w11 = lx * ly;
            const bool vx0 = (x0 >= 0) & (x0 < Wd);
            const bool vx1 = (x1 >= 0) & (x1 < Wd);
            const bool vy0 = (y0 >= 0) & (y0 < Wd);
            const bool vy1 = (y1 >= 0) & (y1 < Wd);

            float4 s = {0.f, 0.f, 0.f, 0.f};
            if (vy0) {
                const float* row = vb + (size_t)(st + y0 * Wd) * 256;
                if (vx0) {
                    const float4 v = *(const float4*)(row + (size_t)x0 * 256);
                    s.x += w00 * v.x; s.y += w00 * v.y; s.z += w00 * v.z; s.w += w00 * v.w;
                }
                if (vx1) {
                    const float4 v = *(const float4*)(row + (size_t)x1 * 256);
                    s.x += w10 * v.x; s.y += w10 * v.y; s.z += w10 * v.z; s.w += w10 * v.w;
                }
            }
            if (vy1) {
                const float* row = vb + (size_t)(st + y1 * Wd) * 256;
                if (vx0) {
                    const float4 v = *(const float4*)(row + (size_t)x0 * 256);
                    s.x += w01 * v.x; s.y += w01 * v.y; s.z += w01 * v.z; s.w += w01 * v.w;
                }
                if (vx1) {
                    const float4 v = *(const float4*)(row + (size_t)x1 * 256);
                    s.x += w11 * v.x; s.y += w11 * v.y; s.z += w11 * v.z; s.w += w11 * v.w;
                }
            }
            acc.x += s.x * aw; acc.y += s.y * aw; acc.z += s.z * aw; acc.w += s.w * aw;
        }
    }

    float* op = out + (qbase + qs) * 256 + h * 32 + d4;
    *(float4*)op = acc;
}

extern "C" void kernel_launch(void* const* d_in, const int* in_sizes, int n_in,
                              void* d_out, int out_size, void* d_ws, size_t ws_size,
                              hipStream_t stream) {
    const float* hs     = (const float*)d_in[0];
    const float* enc    = (const float*)d_in[1];
    const float* refp   = (const float*)d_in[2];
    const float* off_k  = (const float*)d_in[3];
    const float* off_b  = (const float*)d_in[4];
    const float* attn_k = (const float*)d_in[5];
    const float* attn_b = (const float*)d_in[6];
    const float* nps    = (const float*)d_in[7];
    // d_in[8] = spatial_shapes (hardcoded: (80,80),(40,40),(20,20),(10,10))

    float* out      = (float*)d_out;                       // B*Q*C
    float* attn_out = out + (size_t)BB * QQ * NHH * SUMPP * 0 + (size_t)BB * QQ * CC;
    float* loc_ws   = (float*)d_ws;                        // B*Q*NH*SUMP*2 floats

    precompute_kernel<<<BB * QT, 384, 0, stream>>>(hs, refp, off_k, off_b,
                                                   attn_k, attn_b, nps,
                                                   loc_ws, attn_out);
    sample_kernel<<<BB * (QQ / 4), 256, 0, stream>>>(enc, loc_ws, attn_out, out);
}

// Round 2
// 244.427 us; speedup vs baseline: 1.1448x; 1.1448x over previous
//
#include <hip/hip_runtime.h>
#include <math.h>

#define BB 16
#define QQ 300
#define CC 256
#define NHH 8
#define DHH 32
#define SUMPP 16
#define SSS 8500
#define GQ 10
#define QT (QQ / GQ) // 30

// ---------------------------------------------------------------------------
// Kernel A: offsets GEMM + attn GEMM + softmax.
// 384 threads: t<256 -> one offset output (h,p,xy); t>=256 -> one attn logit.
// 10 queries/block; hidden-state reads are block-uniform -> s_load.
// Writes loc as float2 in [q][p*8+h] order and a transposed attn copy so the
// sample kernel can stage LDS with a straight coalesced copy (no transpose).
// ---------------------------------------------------------------------------
__global__ __launch_bounds__(384) void precompute_kernel(
    const float* __restrict__ hs,      // (B,Q,C)
    const float* __restrict__ refp,    // (B,Q,1,4)
    const float* __restrict__ off_k,   // (C,256)
    const float* __restrict__ off_b,   // 256
    const float* __restrict__ attn_k,  // (C,128)
    const float* __restrict__ attn_b,  // 128
    const float* __restrict__ nps,     // 16
    float* __restrict__ loc_t,         // ws: (B,Q,128,2) in [p*8+h][xy]
    float* __restrict__ aw_t,          // ws: (B,Q,128)   in [p*8+h]
    float* __restrict__ attn_out)      // d_out: (B,Q,NH,SUMP) = [h][p]
{
    const int t = threadIdx.x;
    const int blk = blockIdx.x;            // 0..B*QT-1
    const int b = blk / QT;
    const int q0 = (blk % QT) * GQ;
    const float* hsb = hs + ((size_t)b * QQ + q0) * CC;

    float acc[GQ];
#pragma unroll
    for (int g = 0; g < GQ; ++g) acc[g] = 0.f;

    if (t < 256) {
        const int h = t >> 5;
        const int p = (t >> 1) & 15;
        const int xy = t & 1;
        const float* kcol = off_k + t;
#pragma unroll 8
        for (int c = 0; c < CC; ++c) {
            const float k = kcol[c * 256];
#pragma unroll
            for (int g = 0; g < GQ; ++g)
                acc[g] = fmaf(hsb[g * CC + c], k, acc[g]);
        }
        const float scale = nps[p] * 0.5f;  // OFFSET_SCALE = 0.5
        const float bias = off_b[t];
        const int didx = ((p * 8 + h) << 1) | xy;
#pragma unroll
        for (int g = 0; g < GQ; ++g) {
            const float4 r = *(const float4*)(refp + ((size_t)b * QQ + q0 + g) * 4);
            const float center = xy ? r.y : r.x;
            const float wh     = xy ? r.w : r.z;
            loc_t[((size_t)b * QQ + q0 + g) * 256 + didx] =
                fmaf((acc[g] + bias) * scale, wh, center);
        }
    } else {
        const int j = t - 256;             // 0..127 = h*16+p
        const int h = j >> 4;
        const int p = j & 15;
        const float* kcol = attn_k + j;
#pragma unroll 8
        for (int c = 0; c < CC; ++c) {
            const float k = kcol[c * 128];
#pragma unroll
            for (int g = 0; g < GQ; ++g)
                acc[g] = fmaf(hsb[g * CC + c], k, acc[g]);
        }
        const float bias = attn_b[j];
#pragma unroll
        for (int g = 0; g < GQ; ++g) {
            const float logit = acc[g] + bias;
            float m = logit;
#pragma unroll
            for (int o = 1; o < 16; o <<= 1)
                m = fmaxf(m, __shfl_xor(m, o));
            const float e = __expf(logit - m);
            float s = e;
#pragma unroll
            for (int o = 1; o < 16; o <<= 1)
                s += __shfl_xor(s, o);
            const float a = e / s;
            attn_out[((size_t)b * QQ + q0 + g) * 128 + j] = a;
            aw_t[((size_t)b * QQ + q0 + g) * 128 + p * 8 + h] = a;
        }
    }
}

// ---------------------------------------------------------------------------
// Kernel B: bilinear sampling + attention-weighted accumulation.
// Branchless: all 4 corner loads always issued with clamped indices, weights
// zeroed where invalid -> deep software pipelining of the 64 gathers/thread.
// XCD swizzle: b == blockIdx % 8 (mod 16) so each batch's value slab is
// L2-co-located on ~1 XCD.
// ---------------------------------------------------------------------------
__global__ __launch_bounds__(256) void sample_kernel(
    const float* __restrict__ enc,    // (B,S,256)
    const float2* __restrict__ loc2,  // (B,Q,128) float2, [p*8+h]
    const float* __restrict__ aw_t,   // (B,Q,128), [p*8+h]
    float* __restrict__ out)          // (B,Q,256)
{
    __shared__ float2 sh_l[4 * 128];
    __shared__ float  sh_a[4 * 128];

    const int g = blockIdx.x;                // 0..1199
    const int xcd = g & 7;
    const int i = g >> 3;                    // 0..149
    const int b = ((i & 1) << 3) | xcd;      // batch, == g%8 (mod 8)
    const int q0 = (i >> 1) * 4;             // 0..296
    const size_t qbase = (size_t)b * QQ + q0;

    const int t = threadIdx.x;
    const float2* lsrc = loc2 + qbase * 128;
    sh_l[t] = lsrc[t];
    sh_l[t + 256] = lsrc[t + 256];
    const float* asrc = aw_t + qbase * 128;
    sh_a[t] = asrc[t];
    sh_a[t + 256] = asrc[t + 256];
    __syncthreads();

    const int qs = t >> 6;                   // wave id = query sub-index
    const int lane = t & 63;
    const int h = lane >> 3;
    const int d4 = (lane & 7) << 2;
    const float* vb = enc + (size_t)b * SSS * 256 + h * 32 + d4;

    float4 acc = {0.f, 0.f, 0.f, 0.f};

    const int HWs[4]    = {80, 40, 20, 10};
    const int starts[4] = {0, 6400, 8000, 8400};

    int p = 0;
#pragma unroll
    for (int lvl = 0; lvl < 4; ++lvl) {
        const int Wd = HWs[lvl];
        const float Wf = (float)Wd;
        const int st = starts[lvl];
#pragma unroll
        for (int pp = 0; pp < 4; ++pp, ++p) {
            const float2 l = sh_l[qs * 128 + p * 8 + h];
            const float  a = sh_a[qs * 128 + p * 8 + h];

            const float x = l.x * Wf - 0.5f;
            const float y = l.y * Wf - 0.5f;
            const float x0f = floorf(x), y0f = floorf(y);
            const float lx = x - x0f, ly = y - y0f;
            const int x0 = (int)x0f, y0 = (int)y0f;
            const int x1 = x0 + 1, y1 = y0 + 1;

            const bool vx0 = (unsigned)x0 < (unsigned)Wd;
            const bool vx1 = (unsigned)x1 < (unsigned)Wd;
            const bool vy0 = (unsigned)y0 < (unsigned)Wd;
            const bool vy1 = (unsigned)y1 < (unsigned)Wd;

            const int x0c = min(max(x0, 0), Wd - 1);
            const int x1c = min(max(x1, 0), Wd - 1);
            const int y0c = min(max(y0, 0), Wd - 1);
            const int y1c = min(max(y1, 0), Wd - 1);

            float w00 = (1.f - lx) * (1.f - ly) * a;
            float w10 = lx * (1.f - ly) * a;
            float w01 = (1.f - lx) * ly * a;
            float w11 = lx * ly * a;
            w00 = (vx0 & vy0) ? w00 : 0.f;
            w10 = (vx1 & vy0) ? w10 : 0.f;
            w01 = (vx0 & vy1) ? w01 : 0.f;
            w11 = (vx1 & vy1) ? w11 : 0.f;

            const float* r0 = vb + (size_t)(st + y0c * Wd) * 256;
            const float* r1 = vb + (size_t)(st + y1c * Wd) * 256;
            const float4 v00 = *(const float4*)(r0 + ((size_t)x0c << 8));
            const float4 v10 = *(const float4*)(r0 + ((size_t)x1c << 8));
            const float4 v01 = *(const float4*)(r1 + ((size_t)x0c << 8));
            const float4 v11 = *(const float4*)(r1 + ((size_t)x1c << 8));

            acc.x = fmaf(w00, v00.x, fmaf(w10, v10.x, fmaf(w01, v01.x, fmaf(w11, v11.x, acc.x))));
            acc.y = fmaf(w00, v00.y, fmaf(w10, v10.y, fmaf(w01, v01.y, fmaf(w11, v11.y, acc.y))));
            acc.z = fmaf(w00, v00.z, fmaf(w10, v10.z, fmaf(w01, v01.z, fmaf(w11, v11.z, acc.z))));
            acc.w = fmaf(w00, v00.w, fmaf(w10, v10.w, fmaf(w01, v01.w, fmaf(w11, v11.w, acc.w))));
        }
    }

    float* op = out + (qbase + qs) * 256 + h * 32 + d4;
    *(float4*)op = acc;
}

extern "C" void kernel_launch(void* const* d_in, const int* in_sizes, int n_in,
                              void* d_out, int out_size, void* d_ws, size_t ws_size,
                              hipStream_t stream) {
    const float* hs     = (const float*)d_in[0];
    const float* enc    = (const float*)d_in[1];
    const float* refp   = (const float*)d_in[2];
    const float* off_k  = (const float*)d_in[3];
    const float* off_b  = (const float*)d_in[4];
    const float* attn_k = (const float*)d_in[5];
    const float* attn_b = (const float*)d_in[6];
    const float* nps    = (const float*)d_in[7];

    float* out      = (float*)d_out;                       // B*Q*C
    float* attn_out = out + (size_t)BB * QQ * CC;          // B*Q*128
    float* loc_t    = (float*)d_ws;                        // B*Q*256 floats (float2[128])
    float* aw_t     = loc_t + (size_t)BB * QQ * 256;       // B*Q*128 floats

    precompute_kernel<<<BB * QT, 384, 0, stream>>>(hs, refp, off_k, off_b,
                                                   attn_k, attn_b, nps,
                                                   loc_t, aw_t, attn_out);
    sample_kernel<<<BB * (QQ / 4), 256, 0, stream>>>(enc, (const float2*)loc_t,
                                                     aw_t, out);
}

// Round 3
// 243.498 us; speedup vs baseline: 1.1491x; 1.0038x over previous
//
#include <hip/hip_runtime.h>
#include <math.h>

#define BB 16
#define QQ 300
#define CC 256
#define NHH 8
#define DHH 32
#define SUMPP 16
#define SSS 8500
#define GQ 10
#define QT (QQ / GQ) // 30

// ---------------------------------------------------------------------------
// Kernel A: offsets GEMM + attn GEMM + softmax.
// 384 threads: t<256 -> one offset output (h,p,xy); t>=256 -> one attn logit.
// 10 queries/block; hidden-state reads are block-uniform -> s_load.
// Writes loc as float2 in [q][p*8+h] order and a transposed attn copy so the
// sample kernel can stage LDS with a straight coalesced copy (no transpose).
// ---------------------------------------------------------------------------
__global__ __launch_bounds__(384) void precompute_kernel(
    const float* __restrict__ hs,      // (B,Q,C)
    const float* __restrict__ refp,    // (B,Q,1,4)
    const float* __restrict__ off_k,   // (C,256)
    const float* __restrict__ off_b,   // 256
    const float* __restrict__ attn_k,  // (C,128)
    const float* __restrict__ attn_b,  // 128
    const float* __restrict__ nps,     // 16
    float* __restrict__ loc_t,         // ws: (B,Q,128,2) in [p*8+h][xy]
    float* __restrict__ aw_t,          // ws: (B,Q,128)   in [p*8+h]
    float* __restrict__ attn_out)      // d_out: (B,Q,NH,SUMP) = [h][p]
{
    const int t = threadIdx.x;
    const int blk = blockIdx.x;            // 0..B*QT-1
    const int b = blk / QT;
    const int q0 = (blk % QT) * GQ;
    const float* hsb = hs + ((size_t)b * QQ + q0) * CC;

    float acc[GQ];
#pragma unroll
    for (int g = 0; g < GQ; ++g) acc[g] = 0.f;

    if (t < 256) {
        const int h = t >> 5;
        const int p = (t >> 1) & 15;
        const int xy = t & 1;
        const float* kcol = off_k + t;
#pragma unroll 8
        for (int c = 0; c < CC; ++c) {
            const float k = kcol[c * 256];
#pragma unroll
            for (int g = 0; g < GQ; ++g)
                acc[g] = fmaf(hsb[g * CC + c], k, acc[g]);
        }
        const float scale = nps[p] * 0.5f;  // OFFSET_SCALE = 0.5
        const float bias = off_b[t];
        const int didx = ((p * 8 + h) << 1) | xy;
#pragma unroll
        for (int g = 0; g < GQ; ++g) {
            const float4 r = *(const float4*)(refp + ((size_t)b * QQ + q0 + g) * 4);
            const float center = xy ? r.y : r.x;
            const float wh     = xy ? r.w : r.z;
            loc_t[((size_t)b * QQ + q0 + g) * 256 + didx] =
                fmaf((acc[g] + bias) * scale, wh, center);
        }
    } else {
        const int j = t - 256;             // 0..127 = h*16+p
        const int h = j >> 4;
        const int p = j & 15;
        const float* kcol = attn_k + j;
#pragma unroll 8
        for (int c = 0; c < CC; ++c) {
            const float k = kcol[c * 128];
#pragma unroll
            for (int g = 0; g < GQ; ++g)
                acc[g] = fmaf(hsb[g * CC + c], k, acc[g]);
        }
        const float bias = attn_b[j];
#pragma unroll
        for (int g = 0; g < GQ; ++g) {
            const float logit = acc[g] + bias;
            float m = logit;
#pragma unroll
            for (int o = 1; o < 16; o <<= 1)
                m = fmaxf(m, __shfl_xor(m, o));
            const float e = __expf(logit - m);
            float s = e;
#pragma unroll
            for (int o = 1; o < 16; o <<= 1)
                s += __shfl_xor(s, o);
            const float a = e / s;
            attn_out[((size_t)b * QQ + q0 + g) * 128 + j] = a;
            aw_t[((size_t)b * QQ + q0 + g) * 128 + p * 8 + h] = a;
        }
    }
}

// ---------------------------------------------------------------------------
// Kernel B: bilinear sampling + attention-weighted accumulation.
// 2 queries/block, 2 waves per query splitting the 16 points (interleaved so
// each wave sees all 4 levels). 32 gathers/thread, 9600 waves total for
// latency hiding. Branchless clamped gathers; attn folded into corner
// weights; one ds_read_b128 per point ({lx,ly,a,_}); float4 LDS reduction
// across the point-split waves. XCD swizzle keeps each batch's 8.7 MB value
// slab on one XCD's L2.
// ---------------------------------------------------------------------------
__global__ __launch_bounds__(256) void sample_kernel(
    const float* __restrict__ enc,    // (B,S,256)
    const float2* __restrict__ loc2,  // (B,Q,128) float2, [p*8+h]
    const float* __restrict__ aw_t,   // (B,Q,128), [p*8+h]
    float* __restrict__ out)          // (B,Q,256)
{
    __shared__ float4 sh[2 * 128];    // [q][p*8+h] = {lx, ly, a, -}
    __shared__ float4 sh_red[128];    // [q][lane]

    const int g = blockIdx.x;              // 0..2399
    const int xcd = g & 7;
    const int i = g >> 3;                  // 0..299
    const int b = ((i & 1) << 3) | xcd;    // batch
    const int q0 = (i >> 1) * 2;           // 0..298
    const int qbase = b * QQ + q0;

    const int t = threadIdx.x;
    {
        const float2 l = loc2[(size_t)qbase * 128 + t];  // covers both queries
        const float  a = aw_t[(size_t)qbase * 128 + t];
        sh[t] = make_float4(l.x, l.y, a, 0.f);
    }
    __syncthreads();

    const int qs = t >> 7;                 // query sub-index (0..1)
    const int pw = (t >> 6) & 1;           // point-half (0..1)
    const int lane = t & 63;
    const int h = lane >> 3;
    const int d4 = (lane & 7) << 2;
    const float* vb = enc + b * (SSS * 256) + h * 32 + d4;

    float4 acc = {0.f, 0.f, 0.f, 0.f};

    const int HWs[4]    = {80, 40, 20, 10};
    const int starts[4] = {0, 6400, 8000, 8400};

#pragma unroll
    for (int j = 0; j < 8; ++j) {
        const int lvl = j >> 1;
        const int p = 2 * j + pw;          // interleave levels across waves
        const int Wd = HWs[lvl];
        const float Wf = (float)Wd;
        const int st = starts[lvl];

        const float4 lpa = sh[qs * 128 + p * 8 + h];
        const float a = lpa.z;

        const float x = lpa.x * Wf - 0.5f;
        const float y = lpa.y * Wf - 0.5f;
        const float x0f = floorf(x), y0f = floorf(y);
        const float lx = x - x0f, ly = y - y0f;
        const int x0 = (int)x0f, y0 = (int)y0f;
        const int x1 = x0 + 1, y1 = y0 + 1;

        const bool vx0 = (unsigned)x0 < (unsigned)Wd;
        const bool vx1 = (unsigned)x1 < (unsigned)Wd;
        const bool vy0 = (unsigned)y0 < (unsigned)Wd;
        const bool vy1 = (unsigned)y1 < (unsigned)Wd;

        const int x0c = min(max(x0, 0), Wd - 1);
        const int x1c = min(max(x1, 0), Wd - 1);
        const int y0c = min(max(y0, 0), Wd - 1);
        const int y1c = min(max(y1, 0), Wd - 1);

        float w00 = (1.f - lx) * (1.f - ly) * a;
        float w10 = lx * (1.f - ly) * a;
        float w01 = (1.f - lx) * ly * a;
        float w11 = lx * ly * a;
        w00 = (vx0 & vy0) ? w00 : 0.f;
        w10 = (vx1 & vy0) ? w10 : 0.f;
        w01 = (vx0 & vy1) ? w01 : 0.f;
        w11 = (vx1 & vy1) ? w11 : 0.f;

        const int r0 = (st + y0c * Wd) << 8;   // *256 floats
        const int r1 = (st + y1c * Wd) << 8;
        const float4 v00 = *(const float4*)(vb + r0 + (x0c << 8));
        const float4 v10 = *(const float4*)(vb + r0 + (x1c << 8));
        const float4 v01 = *(const float4*)(vb + r1 + (x0c << 8));
        const float4 v11 = *(const float4*)(vb + r1 + (x1c << 8));

        acc.x = fmaf(w00, v00.x, fmaf(w10, v10.x, fmaf(w01, v01.x, fmaf(w11, v11.x, acc.x))));
        acc.y = fmaf(w00, v00.y, fmaf(w10, v10.y, fmaf(w01, v01.y, fmaf(w11, v11.y, acc.y))));
        acc.z = fmaf(w00, v00.z, fmaf(w10, v10.z, fmaf(w01, v01.z, fmaf(w11, v11.z, acc.z))));
        acc.w = fmaf(w00, v00.w, fmaf(w10, v10.w, fmaf(w01, v01.w, fmaf(w11, v11.w, acc.w))));
    }

    if (pw == 1) sh_red[qs * 64 + lane] = acc;
    __syncthreads();
    if (pw == 0) {
        const float4 o = sh_red[qs * 64 + lane];
        acc.x += o.x; acc.y += o.y; acc.z += o.z; acc.w += o.w;
        float* op = out + (size_t)(qbase + qs) * 256 + h * 32 + d4;
        *(float4*)op = acc;
    }
}

extern "C" void kernel_launch(void* const* d_in, const int* in_sizes, int n_in,
                              void* d_out, int out_size, void* d_ws, size_t ws_size,
                              hipStream_t stream) {
    const float* hs     = (const float*)d_in[0];
    const float* enc    = (const float*)d_in[1];
    const float* refp   = (const float*)d_in[2];
    const float* off_k  = (const float*)d_in[3];
    const float* off_b  = (const float*)d_in[4];
    const float* attn_k = (const float*)d_in[5];
    const float* attn_b = (const float*)d_in[6];
    const float* nps    = (const float*)d_in[7];

    float* out      = (float*)d_out;                       // B*Q*C
    float* attn_out = out + (size_t)BB * QQ * CC;          // B*Q*128
    float* loc_t    = (float*)d_ws;                        // B*Q*256 floats (float2[128])
    float* aw_t     = loc_t + (size_t)BB * QQ * 256;       // B*Q*128 floats

    precompute_kernel<<<BB * QT, 384, 0, stream>>>(hs, refp, off_k, off_b,
                                                   attn_k, attn_b, nps,
                                                   loc_t, aw_t, attn_out);
    sample_kernel<<<BB * (QQ / 2), 256, 0, stream>>>(enc, (const float2*)loc_t,
                                                     aw_t, out);
}